// Round 12
// baseline (94.188 us; speedup 1.0000x reference)
//
#include <hip/hip_runtime.h>

// MultiGaussSpatialConv: B=1, N=M=8192, D=3, C=16, fp32.
// out[n,c] = sum_i w_i * (sum_m e_i(n,m) yf[m,c]) / (sum_m e_i(n,m))
// e_i = exp(-d2/(2 s^2)), 1/(2 s^2) = {200, 50, 12.5} -> e0 = e2^16, e1 = e2^4.
//
// R12 (= R10 structure + polynomial exp2). Evidence: R10->R11 halved LDS/B
// traffic with zero effect; R9->R10 cut VALU insts -28% -> main -21%. Kernel
// is VALU-issue-bound with ~61 cyc/slot implied vs ~13 countable -> prime
// suspect is v_exp_f32 transcendental rate (unmeasured on CDNA4). Replace:
//   n = rndne(arg); f = arg-n in [-.5,.5]; 2^f = deg-4 Taylor (rel 6e-5,
//   mostly cancels in num/den); e2 = bit-exponent-add of n. E2x folds into
//   the poly coefficients per-lane (hoisted) - kills the per-slot mul too.
// 12 full-rate VALU/slot replaces 8 + kappa(exp). Decisive: if exp was ~40cyc
// main drops ~2x; if it was 8cyc this loses ~5us (bounded).

static constexpr int Nn = 8192;
static constexpr int Mm = 8192;
static constexpr int NCH = 8;               // m-chunks
static constexpr int NKT = 256 / NCH;       // kt per wave (32)
static constexpr float KC = 36.0673761f;    // 25 * log2(e)
static constexpr float KD = -18.0336880f;   // -12.5 * log2(e)
// 2^f Taylor coefficients, f in [-0.5, 0.5]
static constexpr float P1 = 0.69314718f;
static constexpr float P2 = 0.24022651f;
static constexpr float P3 = 0.05550411f;
static constexpr float P4 = 0.00961813f;

typedef _Float16 half8 __attribute__((ext_vector_type(8)));
typedef __fp16  fp16x2 __attribute__((ext_vector_type(2)));
typedef float  float4v __attribute__((ext_vector_type(4)));

#define MFMA_F16 __builtin_amdgcn_mfma_f32_16x16x32_f16
#define EXP2F(v) __builtin_amdgcn_exp2f(v)

// ---------------- prep: q[m] quad (constant-folded) + yf -> fp16 B-fragments
// frag idx(m,c) = (m>>5)*512 + (((m&31)>>3)*16 + c)*8 + (m&7)
__global__ __launch_bounds__(256) void mgsc_prep(
    const float* __restrict__ y, const float* __restrict__ yf,
    float4* __restrict__ q, _Float16* __restrict__ frag)
{
    const int t = blockIdx.x * 256 + threadIdx.x;   // 0 .. Mm*16-1
    const int m = t >> 4, c = t & 15;
    const int idx = ((m >> 5) << 9) + ((((m & 31) >> 3) << 4) + c) * 8 + (m & 7);
    frag[idx] = (_Float16)yf[t];                    // RNE
    if (t < Mm) {
        const float ax = y[3 * t], ay = y[3 * t + 1], az = y[3 * t + 2];
        q[t] = make_float4(KC * ax, KC * ay, KC * az,
                           KD * (ax * ax + ay * ay + az * az));
    }
}

// ---------------- main: grid (128, NCH); 4 waves/block, one n-tile per wave
__global__ __launch_bounds__(256, 4) void mgsc_main(
    const float* __restrict__ x, const float4* __restrict__ q,
    const _Float16* __restrict__ frag, float* __restrict__ part)
{
    __shared__ float4 qS[NKT * 32];                 // 16 KB: block's q chunk

    const int tid  = threadIdx.x;
    const int wave = tid >> 6, lane = tid & 63;
    const int g    = lane >> 4, c = lane & 15;
    const int xb   = blockIdx.x, yb = blockIdx.y;
    const int n0   = (xb * 4 + wave) * 16;          // this wave's n-tile
    const int nrow = n0 + c;                        // A-frag row for this lane

    // stage q chunk (shared by all 4 waves: same yb)
    const float4* qsrc = q + ((size_t)yb * NKT << 5);
#pragma unroll
    for (int i = 0; i < NKT * 32 / 256; ++i)
        qS[tid + 256 * i] = qsrc[tid + 256 * i];

    const float xx = x[3 * nrow], xy = x[3 * nrow + 1], xz = x[3 * nrow + 2];
    const float E2x = EXP2F(KD * __fmaf_rn(xx, xx, __fmaf_rn(xy, xy, xz * xz)));
    // fold E2x into the 2^f poly coefficients (per-lane, hoisted)
    const float C0 = E2x, C1 = E2x * P1, C2 = E2x * P2, C3 = E2x * P3, C4 = E2x * P4;

    float4v acc0 = {0.f, 0.f, 0.f, 0.f}, acc1 = acc0, acc2 = acc0;
    float4v dac0 = acc0, dac1 = acc0, dac2 = acc0;

    const _Float16 onev = (c == 0) ? (_Float16)1.0f : (_Float16)0.0f;
    half8 bone = {onev, onev, onev, onev, onev, onev, onev, onev};

    __syncthreads();                                // q chunk ready (only barrier)

    const _Float16* fpp = frag + ((size_t)yb * NKT << 9) + (lane << 3);
    half8 Bc = *reinterpret_cast<const half8*>(fpp);

    for (int ktl = 0; ktl < NKT; ++ktl) {
        half8 Bn;
        if (ktl + 1 < NKT) {                        // prefetch next B-frag
            fpp += 512;
            Bn = *reinterpret_cast<const half8*>(fpp);
        }
        const float4* qk = &qS[(ktl << 5) + (g << 3)];
        float E2[8];
#pragma unroll
        for (int j = 0; j < 8; ++j) {
            const float4 Q = qk[j];                 // LDS broadcast (same addr/group)
            const float arg = __fmaf_rn(xx, Q.x,
                              __fmaf_rn(xy, Q.y,
                              __fmaf_rn(xz, Q.z, Q.w)));
            const float nn = __builtin_rintf(arg);  // v_rndne_f32
            const float f  = arg - nn;              // f in [-0.5, 0.5]
            float p = __fmaf_rn(f, C4, C3);
            p = __fmaf_rn(f, p, C2);
            p = __fmaf_rn(f, p, C1);
            p = __fmaf_rn(f, p, C0);                // = E2x * 2^f
            const int sh = ((int)nn) << 23;         // exact: nn integer-valued
            E2[j] = __uint_as_float(__float_as_uint(p) + sh);  // * 2^nn
        }
        union { fp16x2 h2[4]; half8 v; } A2, A1, A0;
#pragma unroll
        for (int jj = 0; jj < 4; ++jj) {
            A2.h2[jj] = __builtin_amdgcn_cvt_pkrtz(E2[2 * jj], E2[2 * jj + 1]);
            const fp16x2 s2 = A2.h2[jj] * A2.h2[jj];    // v_pk_mul_f16
            A1.h2[jj] = s2 * s2;                         // e2^4  (sigma 0.1)
            const fp16x2 s1 = A1.h2[jj] * A1.h2[jj];
            A0.h2[jj] = s1 * s1;                         // e2^16 (sigma 0.05)
        }
        acc0 = MFMA_F16(A0.v, Bc, acc0, 0, 0, 0);
        acc1 = MFMA_F16(A1.v, Bc, acc1, 0, 0, 0);
        acc2 = MFMA_F16(A2.v, Bc, acc2, 0, 0, 0);
        dac0 = MFMA_F16(A0.v, bone, dac0, 0, 0, 0);
        dac1 = MFMA_F16(A1.v, bone, dac1, 0, 0, 0);
        dac2 = MFMA_F16(A2.v, bone, dac2, 0, 0, 0);
        if (ktl + 1 < NKT) Bc = Bn;
    }

    // ---- write this wave's partial: part[yb][n][52], plain stores
    float* pb = part + ((size_t)yb * Nn) * 52;
#pragma unroll
    for (int r = 0; r < 4; ++r) {
        const int n = n0 + (g << 2) + r;            // C/D: col=c, row=g*4+r
        float* row = pb + (size_t)n * 52;
        row[c]      = acc0[r];
        row[16 + c] = acc1[r];
        row[32 + c] = acc2[r];
        if (c == 0) {
            row[48] = dac0[r];
            row[49] = dac1[r];
            row[50] = dac2[r];
        }
    }
}

// ---------------- reduce: thread (n,c) sums NCH chunks, finalizes
__global__ __launch_bounds__(256) void mgsc_reduce(
    const float* __restrict__ part, float* __restrict__ out)
{
    const int t = blockIdx.x * 256 + threadIdx.x;   // 0 .. Nn*16-1
    const int n = t >> 4, c = t & 15;
    float s0 = 0.f, s1 = 0.f, s2 = 0.f, d0 = 0.f, d1 = 0.f, d2 = 0.f;
#pragma unroll
    for (int k = 0; k < NCH; ++k) {
        const float* row = part + ((size_t)k * Nn + n) * 52;
        s0 += row[c];
        s1 += row[16 + c];
        s2 += row[32 + c];
        d0 += row[48];
        d1 += row[49];
        d2 += row[50];
    }
    out[(size_t)n * 16 + c] = 0.3f * s0 / d0 + 0.3f * s1 / d1 + 0.4f * s2 / d2;
}

// ---------------- fused VALU fallback (workspace too small)
__global__ __launch_bounds__(256) void mgsc_fused(
    const float* __restrict__ x, const float* __restrict__ y,
    const float* __restrict__ yf, float* __restrict__ out)
{
    __shared__ float yS[256 * 3];
    __shared__ float yfS[256 * 16];
    const int tid = threadIdx.x;
    const int n   = blockIdx.x * 256 + tid;
    const float xx = x[3 * n], xy = x[3 * n + 1], xz = x[3 * n + 2];
    float a0[16], a1[16], a2[16];
#pragma unroll
    for (int c = 0; c < 16; ++c) { a0[c] = 0.f; a1[c] = 0.f; a2[c] = 0.f; }
    float den0 = 0.f, den1 = 0.f, den2 = 0.f;
    for (int mt = 0; mt < Mm; mt += 256) {
        const float4* ysrc = reinterpret_cast<const float4*>(y + (size_t)mt * 3);
        if (tid < 192) reinterpret_cast<float4*>(yS)[tid] = ysrc[tid];
        const float4* fsrc = reinterpret_cast<const float4*>(yf + (size_t)mt * 16);
#pragma unroll
        for (int k = 0; k < 4; ++k)
            reinterpret_cast<float4*>(yfS)[tid + 256 * k] = fsrc[tid + 256 * k];
        __syncthreads();
        for (int mm = 0; mm < 256; ++mm) {
            const float dx = xx - yS[3 * mm], dy = xy - yS[3 * mm + 1], dz = xz - yS[3 * mm + 2];
            const float d2 = dx * dx + dy * dy + dz * dz;
            const float e2 = __expf(-12.5f * d2);
            const float t = e2 * e2, e1 = t * t, u = e1 * e1, e0 = u * u;
            den0 += e0; den1 += e1; den2 += e2;
            const float4* fr = reinterpret_cast<const float4*>(yfS + mm * 16);
#pragma unroll
            for (int k = 0; k < 4; ++k) {
                const float4 f = fr[k];
                a0[4*k+0] += e0 * f.x; a0[4*k+1] += e0 * f.y; a0[4*k+2] += e0 * f.z; a0[4*k+3] += e0 * f.w;
                a1[4*k+0] += e1 * f.x; a1[4*k+1] += e1 * f.y; a1[4*k+2] += e1 * f.z; a1[4*k+3] += e1 * f.w;
                a2[4*k+0] += e2 * f.x; a2[4*k+1] += e2 * f.y; a2[4*k+2] += e2 * f.z; a2[4*k+3] += e2 * f.w;
            }
        }
        __syncthreads();
    }
    const float r0 = 0.3f / den0, r1 = 0.3f / den1, r2 = 0.4f / den2;
#pragma unroll
    for (int c = 0; c < 16; ++c)
        out[(size_t)n * 16 + c] = a0[c] * r0 + a1[c] * r1 + a2[c] * r2;
}

extern "C" void kernel_launch(void* const* d_in, const int* in_sizes, int n_in,
                              void* d_out, int out_size, void* d_ws, size_t ws_size,
                              hipStream_t stream) {
    const float* x  = (const float*)d_in[0];
    const float* y  = (const float*)d_in[1];
    const float* yf = (const float*)d_in[2];
    float* out = (float*)d_out;

    const size_t qB    = (size_t)Mm * sizeof(float4);            // 128 KB
    const size_t fragB = (size_t)Mm * 16 * sizeof(_Float16);     // 256 KB
    const size_t partB = (size_t)NCH * Nn * 52 * sizeof(float);  // 13.6 MB
    if (qB + fragB + partB > ws_size) {
        mgsc_fused<<<Nn / 256, 256, 0, stream>>>(x, y, yf, out);
        return;
    }
    float4*   q    = (float4*)d_ws;
    _Float16* frag = (_Float16*)((char*)d_ws + qB);
    float*    part = (float*)((char*)d_ws + qB + fragB);

    mgsc_prep<<<(Mm * 16) / 256, 256, 0, stream>>>(y, yf, q, frag);
    mgsc_main<<<dim3(Nn / 64, NCH), 256, 0, stream>>>(x, q, frag, part);
    mgsc_reduce<<<(Nn * 16) / 256, 256, 0, stream>>>(part, out);
}

// Round 13
// 88.318 us; speedup vs baseline: 1.0665x; 1.0665x over previous
//
#include <hip/hip_runtime.h>

// MultiGaussSpatialConv: B=1, N=M=8192, D=3, C=16, fp32.
// out[n,c] = sum_i w_i * (sum_m e_i(n,m) yf[m,c]) / (sum_m e_i(n,m))
// e_i = exp(-d2/(2 s^2)), 1/(2 s^2) = {200, 50, 12.5} -> e0 = e2^16, e1 = e2^4.
//
// R13: packed-fp32 dot products. Evidence chain: wall tracks static VALU count
// (elasticity ~0.75: R9->R10 -28% insts = -21% wall; R12 +33% = +15%), memory
// traffic irrelevant (R11), v_exp_f32 fast (R12). So: cut VALU with VOP3P.
//  - q stored SoA (qx/qy/qz/qw component arrays); ds_read_b128 yields 4
//    consecutive-m values of one component; slot-pairs are natural float2s.
//  - arg for 2 slots = 1 v_pk_add + 3 v_pk_fma (inline asm); E2x folded in
//    as packed +W (arg = KD(|x|^2+|y|^2) + KC x.y, exact same math).
//  - per kt: 16 pk + 8 v_exp + 4 pkrtz + 12 pk_mul_f16 ~= 40 VALU (was ~80).

static constexpr int Nn = 8192;
static constexpr int Mm = 8192;
static constexpr int NCH = 8;               // m-chunks
static constexpr int NKT = 256 / NCH;       // kt per wave (32)
static constexpr float KC = 36.0673761f;    // 25 * log2(e)
static constexpr float KD = -18.0336880f;   // -12.5 * log2(e)

typedef _Float16 half8 __attribute__((ext_vector_type(8)));
typedef __fp16  fp16x2 __attribute__((ext_vector_type(2)));
typedef float  float2v __attribute__((ext_vector_type(2)));
typedef float  float4v __attribute__((ext_vector_type(4)));

#define MFMA_F16 __builtin_amdgcn_mfma_f32_16x16x32_f16
#define EXP2F(v) __builtin_amdgcn_exp2f(v)

__device__ __forceinline__ float2v pk_fma(float2v a, float2v b, float2v c) {
    float2v d;
    asm("v_pk_fma_f32 %0, %1, %2, %3" : "=v"(d) : "v"(a), "v"(b), "v"(c));
    return d;
}
__device__ __forceinline__ float2v pk_add(float2v a, float2v b) {
    float2v d;
    asm("v_pk_add_f32 %0, %1, %2" : "=v"(d) : "v"(a), "v"(b));
    return d;
}

// ---------------- prep: q SoA (constant-folded) + yf -> fp16 B-fragments
// frag idx(m,c) = (m>>5)*512 + (((m&31)>>3)*16 + c)*8 + (m&7)
__global__ __launch_bounds__(256) void mgsc_prep(
    const float* __restrict__ y, const float* __restrict__ yf,
    float* __restrict__ q, _Float16* __restrict__ frag)
{
    const int t = blockIdx.x * 256 + threadIdx.x;   // 0 .. Mm*16-1
    const int m = t >> 4, c = t & 15;
    const int idx = ((m >> 5) << 9) + ((((m & 31) >> 3) << 4) + c) * 8 + (m & 7);
    frag[idx] = (_Float16)yf[t];                    // RNE
    if (t < Mm) {
        const float ax = y[3 * t], ay = y[3 * t + 1], az = y[3 * t + 2];
        q[t]          = KC * ax;                    // qx
        q[Mm + t]     = KC * ay;                    // qy
        q[2 * Mm + t] = KC * az;                    // qz
        q[3 * Mm + t] = KD * (ax * ax + ay * ay + az * az);  // qw
    }
}

// ---------------- main: grid (128, NCH); 4 waves/block, one n-tile per wave
__global__ __launch_bounds__(256, 4) void mgsc_main(
    const float* __restrict__ x, const float* __restrict__ q,
    const _Float16* __restrict__ frag, float* __restrict__ part)
{
    __shared__ float qS[4][NKT * 32];               // 16 KB SoA: block's q chunk

    const int tid  = threadIdx.x;
    const int wave = tid >> 6, lane = tid & 63;
    const int g    = lane >> 4, c = lane & 15;
    const int xb   = blockIdx.x, yb = blockIdx.y;
    const int n0   = (xb * 4 + wave) * 16;          // this wave's n-tile
    const int nrow = n0 + c;                        // A-frag row for this lane

    // stage q chunk SoA (shared by all 4 waves: same yb); 1024 floats/comp
#pragma unroll
    for (int comp = 0; comp < 4; ++comp) {
        const float4* src = reinterpret_cast<const float4*>(q + (size_t)comp * Mm + yb * (NKT * 32));
        reinterpret_cast<float4*>(qS[comp])[tid] = src[tid];
    }

    const float xx = x[3 * nrow], xy = x[3 * nrow + 1], xz = x[3 * nrow + 2];
    const float W = KD * __fmaf_rn(xx, xx, __fmaf_rn(xy, xy, xz * xz));
    const float2v xx2 = {xx, xx}, xy2 = {xy, xy}, xz2 = {xz, xz}, W2 = {W, W};

    float4v acc0 = {0.f, 0.f, 0.f, 0.f}, acc1 = acc0, acc2 = acc0;
    float4v dac0 = acc0, dac1 = acc0, dac2 = acc0;

    const _Float16 onev = (c == 0) ? (_Float16)1.0f : (_Float16)0.0f;
    half8 bone = {onev, onev, onev, onev, onev, onev, onev, onev};

    __syncthreads();                                // q chunk ready (only barrier)

    const _Float16* fpp = frag + ((size_t)yb * NKT << 9) + (lane << 3);
    half8 Bc = *reinterpret_cast<const half8*>(fpp);

    for (int ktl = 0; ktl < NKT; ++ktl) {
        half8 Bn;
        if (ktl + 1 < NKT) {                        // prefetch next B-frag
            fpp += 512;
            Bn = *reinterpret_cast<const half8*>(fpp);
        }
        const int qb = (ktl << 5) + (g << 3);
        // 8 ds_read_b128: 2 per component, conflict-free (bases 32B apart)
        const float4v X0 = *reinterpret_cast<const float4v*>(&qS[0][qb]);
        const float4v X1 = *reinterpret_cast<const float4v*>(&qS[0][qb + 4]);
        const float4v Y0 = *reinterpret_cast<const float4v*>(&qS[1][qb]);
        const float4v Y1 = *reinterpret_cast<const float4v*>(&qS[1][qb + 4]);
        const float4v Z0 = *reinterpret_cast<const float4v*>(&qS[2][qb]);
        const float4v Z1 = *reinterpret_cast<const float4v*>(&qS[2][qb + 4]);
        const float4v Wv0 = *reinterpret_cast<const float4v*>(&qS[3][qb]);
        const float4v Wv1 = *reinterpret_cast<const float4v*>(&qS[3][qb + 4]);

        float2v Xp[4], Yp[4], Zp[4], Wp[4];
        Xp[0] = __builtin_shufflevector(X0, X0, 0, 1); Xp[1] = __builtin_shufflevector(X0, X0, 2, 3);
        Xp[2] = __builtin_shufflevector(X1, X1, 0, 1); Xp[3] = __builtin_shufflevector(X1, X1, 2, 3);
        Yp[0] = __builtin_shufflevector(Y0, Y0, 0, 1); Yp[1] = __builtin_shufflevector(Y0, Y0, 2, 3);
        Yp[2] = __builtin_shufflevector(Y1, Y1, 0, 1); Yp[3] = __builtin_shufflevector(Y1, Y1, 2, 3);
        Zp[0] = __builtin_shufflevector(Z0, Z0, 0, 1); Zp[1] = __builtin_shufflevector(Z0, Z0, 2, 3);
        Zp[2] = __builtin_shufflevector(Z1, Z1, 0, 1); Zp[3] = __builtin_shufflevector(Z1, Z1, 2, 3);
        Wp[0] = __builtin_shufflevector(Wv0, Wv0, 0, 1); Wp[1] = __builtin_shufflevector(Wv0, Wv0, 2, 3);
        Wp[2] = __builtin_shufflevector(Wv1, Wv1, 0, 1); Wp[3] = __builtin_shufflevector(Wv1, Wv1, 2, 3);

        union { fp16x2 h2[4]; half8 v; } A2, A1, A0;
#pragma unroll
        for (int p = 0; p < 4; ++p) {
            // arg pair = KD(|x|^2+|y|^2) + KC x.y   (1 pk_add + 3 pk_fma)
            float2v a = pk_add(Wp[p], W2);
            a = pk_fma(xz2, Zp[p], a);
            a = pk_fma(xy2, Yp[p], a);
            a = pk_fma(xx2, Xp[p], a);
            const float e_lo = EXP2F(a.x);          // v_exp_f32 (fast, R12)
            const float e_hi = EXP2F(a.y);
            A2.h2[p] = __builtin_amdgcn_cvt_pkrtz(e_lo, e_hi);
            const fp16x2 s2 = A2.h2[p] * A2.h2[p];  // v_pk_mul_f16
            A1.h2[p] = s2 * s2;                     // e2^4  (sigma 0.1)
            const fp16x2 s1 = A1.h2[p] * A1.h2[p];
            A0.h2[p] = s1 * s1;                     // e2^16 (sigma 0.05)
        }
        acc0 = MFMA_F16(A0.v, Bc, acc0, 0, 0, 0);
        acc1 = MFMA_F16(A1.v, Bc, acc1, 0, 0, 0);
        acc2 = MFMA_F16(A2.v, Bc, acc2, 0, 0, 0);
        dac0 = MFMA_F16(A0.v, bone, dac0, 0, 0, 0);
        dac1 = MFMA_F16(A1.v, bone, dac1, 0, 0, 0);
        dac2 = MFMA_F16(A2.v, bone, dac2, 0, 0, 0);
        if (ktl + 1 < NKT) Bc = Bn;
    }

    // ---- write this wave's partial: part[yb][n][52], plain stores
    float* pb = part + ((size_t)yb * Nn) * 52;
#pragma unroll
    for (int r = 0; r < 4; ++r) {
        const int n = n0 + (g << 2) + r;            // C/D: col=c, row=g*4+r
        float* row = pb + (size_t)n * 52;
        row[c]      = acc0[r];
        row[16 + c] = acc1[r];
        row[32 + c] = acc2[r];
        if (c == 0) {
            row[48] = dac0[r];
            row[49] = dac1[r];
            row[50] = dac2[r];
        }
    }
}

// ---------------- reduce: thread (n,c) sums NCH chunks, finalizes
__global__ __launch_bounds__(256) void mgsc_reduce(
    const float* __restrict__ part, float* __restrict__ out)
{
    const int t = blockIdx.x * 256 + threadIdx.x;   // 0 .. Nn*16-1
    const int n = t >> 4, c = t & 15;
    float s0 = 0.f, s1 = 0.f, s2 = 0.f, d0 = 0.f, d1 = 0.f, d2 = 0.f;
#pragma unroll
    for (int k = 0; k < NCH; ++k) {
        const float* row = part + ((size_t)k * Nn + n) * 52;
        s0 += row[c];
        s1 += row[16 + c];
        s2 += row[32 + c];
        d0 += row[48];
        d1 += row[49];
        d2 += row[50];
    }
    out[(size_t)n * 16 + c] = 0.3f * s0 / d0 + 0.3f * s1 / d1 + 0.4f * s2 / d2;
}

// ---------------- fused VALU fallback (workspace too small)
__global__ __launch_bounds__(256) void mgsc_fused(
    const float* __restrict__ x, const float* __restrict__ y,
    const float* __restrict__ yf, float* __restrict__ out)
{
    __shared__ float yS[256 * 3];
    __shared__ float yfS[256 * 16];
    const int tid = threadIdx.x;
    const int n   = blockIdx.x * 256 + tid;
    const float xx = x[3 * n], xy = x[3 * n + 1], xz = x[3 * n + 2];
    float a0[16], a1[16], a2[16];
#pragma unroll
    for (int c = 0; c < 16; ++c) { a0[c] = 0.f; a1[c] = 0.f; a2[c] = 0.f; }
    float den0 = 0.f, den1 = 0.f, den2 = 0.f;
    for (int mt = 0; mt < Mm; mt += 256) {
        const float4* ysrc = reinterpret_cast<const float4*>(y + (size_t)mt * 3);
        if (tid < 192) reinterpret_cast<float4*>(yS)[tid] = ysrc[tid];
        const float4* fsrc = reinterpret_cast<const float4*>(yf + (size_t)mt * 16);
#pragma unroll
        for (int k = 0; k < 4; ++k)
            reinterpret_cast<float4*>(yfS)[tid + 256 * k] = fsrc[tid + 256 * k];
        __syncthreads();
        for (int mm = 0; mm < 256; ++mm) {
            const float dx = xx - yS[3 * mm], dy = xy - yS[3 * mm + 1], dz = xz - yS[3 * mm + 2];
            const float d2 = dx * dx + dy * dy + dz * dz;
            const float e2 = __expf(-12.5f * d2);
            const float t = e2 * e2, e1 = t * t, u = e1 * e1, e0 = u * u;
            den0 += e0; den1 += e1; den2 += e2;
            const float4* fr = reinterpret_cast<const float4*>(yfS + mm * 16);
#pragma unroll
            for (int k = 0; k < 4; ++k) {
                const float4 f = fr[k];
                a0[4*k+0] += e0 * f.x; a0[4*k+1] += e0 * f.y; a0[4*k+2] += e0 * f.z; a0[4*k+3] += e0 * f.w;
                a1[4*k+0] += e1 * f.x; a1[4*k+1] += e1 * f.y; a1[4*k+2] += e1 * f.z; a1[4*k+3] += e1 * f.w;
                a2[4*k+0] += e2 * f.x; a2[4*k+1] += e2 * f.y; a2[4*k+2] += e2 * f.z; a2[4*k+3] += e2 * f.w;
            }
        }
        __syncthreads();
    }
    const float r0 = 0.3f / den0, r1 = 0.3f / den1, r2 = 0.4f / den2;
#pragma unroll
    for (int c = 0; c < 16; ++c)
        out[(size_t)n * 16 + c] = a0[c] * r0 + a1[c] * r1 + a2[c] * r2;
}

extern "C" void kernel_launch(void* const* d_in, const int* in_sizes, int n_in,
                              void* d_out, int out_size, void* d_ws, size_t ws_size,
                              hipStream_t stream) {
    const float* x  = (const float*)d_in[0];
    const float* y  = (const float*)d_in[1];
    const float* yf = (const float*)d_in[2];
    float* out = (float*)d_out;

    const size_t qB    = (size_t)4 * Mm * sizeof(float);         // 128 KB SoA
    const size_t fragB = (size_t)Mm * 16 * sizeof(_Float16);     // 256 KB
    const size_t partB = (size_t)NCH * Nn * 52 * sizeof(float);  // 13.6 MB
    if (qB + fragB + partB > ws_size) {
        mgsc_fused<<<Nn / 256, 256, 0, stream>>>(x, y, yf, out);
        return;
    }
    float*    q    = (float*)d_ws;
    _Float16* frag = (_Float16*)((char*)d_ws + qB);
    float*    part = (float*)((char*)d_ws + qB + fragB);

    mgsc_prep<<<(Mm * 16) / 256, 256, 0, stream>>>(y, yf, q, frag);
    mgsc_main<<<dim3(Nn / 64, NCH), 256, 0, stream>>>(x, q, frag, part);
    mgsc_reduce<<<(Nn * 16) / 256, 256, 0, stream>>>(part, out);
}